// Round 4
// baseline (129.163 us; speedup 1.0000x reference)
//
#include <hip/hip_runtime.h>
#include <hip/hip_bf16.h>

// LiftSplatShoot collapsed form:
//   out[b,n,i,p,d] = a_i[b,n,p] * depths[d] + E[b,n,i,3]
//   a_i[p] = sum_j E[i,j] * (Kinv[j,:] . [x,y,1]) * softmax_HW(feat)[j,p]
// B=2,N=6,C=3,H=64,W=176,D=64. Output 104 MB fp32 -> write-BW bound (~17us).
//
// Single fused kernel: each block recomputes the 3 per-row softmax
// denominators it needs (feat is 1.6 MB -> L2-resident; 135 KB/block of L2
// reads, ~285 MB aggregate ~ 8us @ L2 BW, overlapped with stores).
// Max-subtraction dropped: inputs are N(0,1), exp() safe, fp32 error ~1e-6
// vs threshold 4.7e-2.

#define BN    12
#define CCH   3
#define HH    64
#define WW    176
#define HWSZ  (HH * WW)      // 11264
#define DD    64
#define PIX   64             // pixels per block
#define TILES (HWSZ / PIX)   // 176

// clang-native vec4 for __builtin_nontemporal_store (HIP float4 is a class).
typedef float fvec4 __attribute__((ext_vector_type(4)));

__global__ __launch_bounds__(256) void lss_fused(
    const float* __restrict__ feat, const float* __restrict__ intr,
    const float* __restrict__ extr, const float* __restrict__ depths,
    float* __restrict__ out) {
  const int blk = blockIdx.x;
  const int bn = blk / TILES;
  const int tile = blk - bn * TILES;
  const int p0 = tile * PIX;
  const int t = threadIdx.x;
  const int wave = t >> 6, lane = t & 63;

  __shared__ float sred[CCH][4];  // per-wave partial sums per row
  __shared__ float sinv[CCH];     // 1 / sum(exp(row))
  __shared__ float s_s[CCH][PIX]; // rays_c * prob_c

  // ---- Phase 0: per-row sum of exp (one pass, no max-sub) ----
  // Row = 11264 fp32 = 2816 fvec4 = 11 fvec4/thread.
#pragma unroll
  for (int r = 0; r < CCH; ++r) {
    const fvec4* rp = (const fvec4*)(feat + ((size_t)bn * CCH + r) * HWSZ);
    float s = 0.f;
#pragma unroll
    for (int k = 0; k < 11; ++k) {
      const fvec4 v = rp[t + 256 * k];
      s += __expf(v.x) + __expf(v.y) + __expf(v.z) + __expf(v.w);
    }
#pragma unroll
    for (int off = 32; off > 0; off >>= 1) s += __shfl_down(s, off, 64);
    if (lane == 0) sred[r][wave] = s;
  }
  __syncthreads();
  if (t < CCH)
    sinv[t] = 1.0f / (sred[t][0] + sred[t][1] + sred[t][2] + sred[t][3]);
  __syncthreads();

  // ---- Phase A: s_c = ray_c * prob_c for this block's 64 pixels ----
  // 3x3 inverse of intrinsics upper-left block (uniform per block)
  const float* Kp = intr + bn * 16;
  const float a = Kp[0], b = Kp[1], c = Kp[2];
  const float d = Kp[4], e = Kp[5], f = Kp[6];
  const float g = Kp[8], h = Kp[9], i9 = Kp[10];
  const float A0 = e * i9 - f * h;
  const float B0 = -(d * i9 - f * g);
  const float C0 = d * h - e * g;
  const float invdet = 1.0f / (a * A0 + b * B0 + c * C0);

  if (t < 192) {
    const int cc = t >> 6;   // channel, wave-uniform
    const int pl = t & 63;   // pixel in tile
    const int p = p0 + pl;
    const float fv = feat[((size_t)bn * CCH + cc) * HWSZ + p];
    const float prob = __expf(fv) * sinv[cc];
    const float x = (float)(p % WW);
    const float y = (float)(p / WW);
    float r0, r1, r2;
    if (cc == 0) {
      r0 = A0 * invdet; r1 = -(b * i9 - c * h) * invdet;
      r2 = (b * f - c * e) * invdet;
    } else if (cc == 1) {
      r0 = B0 * invdet; r1 = (a * i9 - c * g) * invdet;
      r2 = -(a * f - c * d) * invdet;
    } else {
      r0 = C0 * invdet; r1 = -(a * h - b * g) * invdet;
      r2 = (a * e - b * d) * invdet;
    }
    s_s[cc][pl] = (r0 * x + r1 * y + r2) * prob;
  }

  const float* Ep = extr + bn * 16;
  const float e00 = Ep[0], e01 = Ep[1], e02 = Ep[2], e03 = Ep[3];
  const float e10 = Ep[4], e11 = Ep[5], e12 = Ep[6], e13 = Ep[7];
  const float e20 = Ep[8], e21 = Ep[9], e22 = Ep[10], e23 = Ep[11];

  __syncthreads();

  // ---- Phase B: stream 12 NT float4 stores/thread (48 KB/block) ----
  const int dq = t & 15;    // depth quad
  const int plb = t >> 4;   // 0..15, pixel-within-group
  const fvec4 dep = ((const fvec4*)depths)[dq];
  fvec4* outq = (fvec4*)out;
  const size_t base0 = ((size_t)(bn * CCH + 0) * HWSZ + p0) * (DD / 4) + dq;
  const size_t base1 = ((size_t)(bn * CCH + 1) * HWSZ + p0) * (DD / 4) + dq;
  const size_t base2 = ((size_t)(bn * CCH + 2) * HWSZ + p0) * (DD / 4) + dq;

#pragma unroll
  for (int gq = 0; gq < 4; ++gq) {
    const int pl = gq * 16 + plb;
    const float s0 = s_s[0][pl], s1 = s_s[1][pl], s2 = s_s[2][pl];
    const float a0 = e00 * s0 + e01 * s1 + e02 * s2;
    const float a1 = e10 * s0 + e11 * s1 + e12 * s2;
    const float a2 = e20 * s0 + e21 * s1 + e22 * s2;
    fvec4 o;
    o.x = a0 * dep.x + e03; o.y = a0 * dep.y + e03;
    o.z = a0 * dep.z + e03; o.w = a0 * dep.w + e03;
    __builtin_nontemporal_store(o, &outq[base0 + (size_t)pl * (DD / 4)]);
    o.x = a1 * dep.x + e13; o.y = a1 * dep.y + e13;
    o.z = a1 * dep.z + e13; o.w = a1 * dep.w + e13;
    __builtin_nontemporal_store(o, &outq[base1 + (size_t)pl * (DD / 4)]);
    o.x = a2 * dep.x + e23; o.y = a2 * dep.y + e23;
    o.z = a2 * dep.z + e23; o.w = a2 * dep.w + e23;
    __builtin_nontemporal_store(o, &outq[base2 + (size_t)pl * (DD / 4)]);
  }
}

extern "C" void kernel_launch(void* const* d_in, const int* in_sizes, int n_in,
                              void* d_out, int out_size, void* d_ws,
                              size_t ws_size, hipStream_t stream) {
  const float* feat = (const float*)d_in[0];    // (12,3,11264)
  const float* intr = (const float*)d_in[1];    // (2,6,4,4)
  const float* extr = (const float*)d_in[2];    // (2,6,4,4)
  // d_in[3] = xy1 (recomputed analytically), d_in[4] = depths
  const float* depths = (const float*)d_in[4];  // (64,)
  float* out = (float*)d_out;

  lss_fused<<<BN * TILES, 256, 0, stream>>>(feat, intr, extr, depths, out);
}

// Round 5
// 119.425 us; speedup vs baseline: 1.0815x; 1.0815x over previous
//
#include <hip/hip_runtime.h>
#include <hip/hip_bf16.h>

// LiftSplatShoot collapsed form:
//   out[b,n,i,p,d] = a_i[b,n,p] * depths[d] + E[b,n,i,3]
//   a_i[p] = sum_j E[i,j] * (Kinv[j,:] . [x,y,1]) * softmax_HW(feat)[j,p]
// B=2,N=6,C=3,H=64,W=176,D=64. Output 104 MB fp32 -> write-BW bound (~17us).
//
// Two kernels: (1) per-row softmax stats (36 rows), (2) barrier-free main
// kernel: each thread owns (pixel, depth-quad), recomputes probs/rays/a_i
// inline (redundant x16 but ~100 VALU ops) and streams 3 float4 stores with
// no LDS and no __syncthreads.

#define BN    12
#define CCH   3
#define HH    64
#define WW    176
#define HWSZ  (HH * WW)      // 11264
#define DD    64
#define PIX   16             // pixels per block in main kernel
#define TILES (HWSZ / PIX)   // 704

typedef float fvec4 __attribute__((ext_vector_type(4)));

// ---------------- Kernel 1: per-(bn,c) softmax stats --------------------
// 36 blocks, 256 threads. Row of 11264 fp32 = 2816 float4 = 11 float4/thread.
__global__ __launch_bounds__(256) void lss_softmax_stats(
    const float* __restrict__ feat, float* __restrict__ mx_out,
    float* __restrict__ invsum_out) {
  const int row = blockIdx.x;  // 0..35  (bn*3 + c)
  const int t = threadIdx.x;
  const fvec4* rp = (const fvec4*)(feat + (size_t)row * HWSZ);

  fvec4 v[11];
  float m = -3.4e38f;
#pragma unroll
  for (int k = 0; k < 11; ++k) {
    v[k] = rp[t + 256 * k];
    m = fmaxf(m, fmaxf(fmaxf(v[k].x, v[k].y), fmaxf(v[k].z, v[k].w)));
  }
#pragma unroll
  for (int off = 32; off > 0; off >>= 1) m = fmaxf(m, __shfl_down(m, off, 64));

  __shared__ float smax[4];
  __shared__ float ssum[4];
  const int wave = t >> 6, lane = t & 63;
  if (lane == 0) smax[wave] = m;
  __syncthreads();
  if (t == 0)
    smax[0] = fmaxf(fmaxf(smax[0], smax[1]), fmaxf(smax[2], smax[3]));
  __syncthreads();
  m = smax[0];

  float s = 0.f;
#pragma unroll
  for (int k = 0; k < 11; ++k) {
    s += __expf(v[k].x - m) + __expf(v[k].y - m) + __expf(v[k].z - m) +
         __expf(v[k].w - m);
  }
#pragma unroll
  for (int off = 32; off > 0; off >>= 1) s += __shfl_down(s, off, 64);
  if (lane == 0) ssum[wave] = s;
  __syncthreads();
  if (t == 0) {
    mx_out[row] = m;
    invsum_out[row] = 1.0f / (ssum[0] + ssum[1] + ssum[2] + ssum[3]);
  }
}

// ---------------- Kernel 2: barrier-free main kernel --------------------
// grid = BN*TILES (8448) blocks x 256 threads. Thread = (pixel, depth-quad).
// No LDS, no barriers: load 3 feats (16-lane broadcast), compute everything
// inline, issue 3 coalesced float4 stores (1 KB contiguous per wave-store).
__global__ __launch_bounds__(256) void lss_main(
    const float* __restrict__ feat, const float* __restrict__ intr,
    const float* __restrict__ extr, const float* __restrict__ depths,
    const float* __restrict__ mx, const float* __restrict__ invsum,
    float* __restrict__ out) {
  const int blk = blockIdx.x;
  const int bn = blk / TILES;
  const int tile = blk - bn * TILES;
  const int t = threadIdx.x;
  const int pl = t >> 4;   // pixel in tile, 0..15
  const int dq = t & 15;   // depth quad
  const int p = tile * PIX + pl;

  // Per-row softmax scale (uniform per block row-group; L1 broadcast)
  const float is0 = invsum[bn * CCH + 0], m0 = mx[bn * CCH + 0];
  const float is1 = invsum[bn * CCH + 1], m1 = mx[bn * CCH + 1];
  const float is2 = invsum[bn * CCH + 2], m2 = mx[bn * CCH + 2];

  const float f0 = feat[((size_t)bn * CCH + 0) * HWSZ + p];
  const float f1 = feat[((size_t)bn * CCH + 1) * HWSZ + p];
  const float f2 = feat[((size_t)bn * CCH + 2) * HWSZ + p];

  // 3x3 inverse of intrinsics upper-left block (uniform per block)
  const float* Kp = intr + bn * 16;
  const float a = Kp[0], b = Kp[1], c = Kp[2];
  const float d = Kp[4], e = Kp[5], f = Kp[6];
  const float g = Kp[8], h = Kp[9], i9 = Kp[10];
  const float A0 = e * i9 - f * h;
  const float B0 = -(d * i9 - f * g);
  const float C0 = d * h - e * g;
  const float invdet = 1.0f / (a * A0 + b * B0 + c * C0);

  const float x = (float)(p % WW);
  const float y = (float)(p / WW);
  const float r0 = (A0 * x - (b * i9 - c * h) * y + (b * f - c * e)) * invdet;
  const float r1 = (B0 * x + (a * i9 - c * g) * y - (a * f - c * d)) * invdet;
  const float r2 = (C0 * x - (a * h - b * g) * y + (a * e - b * d)) * invdet;

  const float s0 = r0 * __expf(f0 - m0) * is0;
  const float s1 = r1 * __expf(f1 - m1) * is1;
  const float s2 = r2 * __expf(f2 - m2) * is2;

  const float* Ep = extr + bn * 16;
  const float a0 = Ep[0] * s0 + Ep[1] * s1 + Ep[2] * s2;
  const float a1 = Ep[4] * s0 + Ep[5] * s1 + Ep[6] * s2;
  const float a2 = Ep[8] * s0 + Ep[9] * s1 + Ep[10] * s2;
  const float t0 = Ep[3], t1 = Ep[7], t2 = Ep[11];

  const fvec4 dep = ((const fvec4*)depths)[dq];
  fvec4* outq = (fvec4*)out;
  const size_t pb = (size_t)p * (DD / 4) + dq;

  fvec4 o;
  o.x = a0 * dep.x + t0; o.y = a0 * dep.y + t0;
  o.z = a0 * dep.z + t0; o.w = a0 * dep.w + t0;
  outq[(size_t)(bn * CCH + 0) * HWSZ * (DD / 4) + pb] = o;
  o.x = a1 * dep.x + t1; o.y = a1 * dep.y + t1;
  o.z = a1 * dep.z + t1; o.w = a1 * dep.w + t1;
  outq[(size_t)(bn * CCH + 1) * HWSZ * (DD / 4) + pb] = o;
  o.x = a2 * dep.x + t2; o.y = a2 * dep.y + t2;
  o.z = a2 * dep.z + t2; o.w = a2 * dep.w + t2;
  outq[(size_t)(bn * CCH + 2) * HWSZ * (DD / 4) + pb] = o;
}

extern "C" void kernel_launch(void* const* d_in, const int* in_sizes, int n_in,
                              void* d_out, int out_size, void* d_ws,
                              size_t ws_size, hipStream_t stream) {
  const float* feat = (const float*)d_in[0];    // (12,3,11264)
  const float* intr = (const float*)d_in[1];    // (2,6,4,4)
  const float* extr = (const float*)d_in[2];    // (2,6,4,4)
  // d_in[3] = xy1 (recomputed analytically), d_in[4] = depths
  const float* depths = (const float*)d_in[4];  // (64,)
  float* out = (float*)d_out;

  float* mx = (float*)d_ws;          // 36 floats
  float* invsum = mx + 64;           // 36 floats (64-offset for alignment)

  lss_softmax_stats<<<BN * CCH, 256, 0, stream>>>(feat, mx, invsum);
  lss_main<<<BN * TILES, 256, 0, stream>>>(feat, intr, extr, depths, mx,
                                           invsum, out);
}